// Round 12
// baseline (273.776 us; speedup 1.0000x reference)
//
#include <hip/hip_runtime.h>

// CausalLinearRelativeAttention — chunked 3-branch causal linear attention, bf16 MFMA.
// N=4, L=2048, H=8, D=Dv=128, chunk C=128, T=16 chunks, 3 branches (coeff -2 folded into Qb2).
// R8: dropped kbt3. R11: k_kvfeat+p1a fused (k_kvs). R15: sct-prefix merged into kqm (266.6us).
// R16: proj (q2@omega -> sin^2) moved OUT of kqm INTO the k_kvs dispatch as disjoint blocks
//      512..1023 (independent of k_kvs; overlaps its latency-padded window). sin^2 stored as
//      bf16 s2 (16MB, same f2b bits as the old LDS round trip); kqm's qfeat blocks become a
//      single streaming pass reading s2. Bit-exact vs R15 everywhere.

typedef float f32x4 __attribute__((ext_vector_type(4)));
typedef short s16x8 __attribute__((ext_vector_type(8)));
typedef short s16x4 __attribute__((ext_vector_type(4)));
typedef unsigned short u16;

static constexpr int    Ln   = 2048;
static constexpr size_t NHLD = (size_t)32 * 2048 * 128; // per-branch feature elems = 8,388,608
static constexpr size_t KSB  = (size_t)32 * 16 * 128;   // kspre per-branch stride = 65536

__device__ __forceinline__ float b2f(u16 s) {
  union { unsigned u; float f; } x; x.u = ((unsigned)s) << 16; return x.f;
}
__device__ __forceinline__ u16 f2b(float f) {
  union { float f; unsigned u; } x; x.f = f;
  unsigned r = x.u + 0x7fffu + ((x.u >> 16) & 1u);
  return (u16)(r >> 16);
}
__device__ __forceinline__ s16x8 pack8(f32x4 a, f32x4 b) {
  s16x8 r;
  r[0] = (short)f2b(a[0]); r[1] = (short)f2b(a[1]); r[2] = (short)f2b(a[2]); r[3] = (short)f2b(a[3]);
  r[4] = (short)f2b(b[0]); r[5] = (short)f2b(b[1]); r[6] = (short)f2b(b[2]); r[7] = (short)f2b(b[3]);
  return r;
}

// ---------------------------------------------------------------- K0: omega^T (bf16) + column sums
__global__ __launch_bounds__(256) void k_omega(const float* __restrict__ om,
                                               u16* __restrict__ wt, float* __restrict__ osum) {
  __shared__ alignas(16) u16 T[128][136];
  int h = blockIdx.x, t = threadIdx.x;
  for (int idx = t; idx < 128 * 32; idx += 256) {
    int i = idx >> 5, cs = (idx & 31) << 2;
    f32x4 vv = *(const f32x4*)(om + ((size_t)(h * 128 + i)) * 128 + cs);
    T[i][cs + 0] = f2b(vv[0]); T[i][cs + 1] = f2b(vv[1]);
    T[i][cs + 2] = f2b(vv[2]); T[i][cs + 3] = f2b(vv[3]);
  }
  if (t < 128) { // exact fp32 column sums (coalesced per row)
    float acc = 0.f;
    for (int i = 0; i < 128; i++) acc += om[((size_t)(h * 128 + i)) * 128 + t];
    osum[h * 128 + t] = acc;
  }
  __syncthreads();
  { // transposed write: wt[h][j][i] = omega[h][i][j]
    int j = t >> 1, lh = (t & 1) << 6;
    s16x8* dst = (s16x8*)(wt + ((size_t)(h * 128 + j)) * 128 + lh);
    for (int u = 0; u < 8; u++) {
      s16x8 pv;
#pragma unroll
      for (int e = 0; e < 8; e++) pv[e] = (short)T[lh + u * 8 + e][j];
      dst[u] = pv;
    }
  }
}

// ---------------------- KVSP: blocks 0..511 = k_kvs body (R11 verbatim);
// blocks 512..1023 = proj body (q2@omega MFMA -> sin^2 -> s2 bf16 stream), independent work
// that overlaps k_kvs's latency-padded window. 512 threads both.
__global__ __launch_bounds__(512) void kvsp(const float* __restrict__ kg, const float* __restrict__ vg,
                                            const float* __restrict__ klg, const float* __restrict__ osum,
                                            u16* __restrict__ kb3, u16* __restrict__ vt,
                                            u16* __restrict__ sct, float* __restrict__ ksum,
                                            const float* __restrict__ q2g, const u16* __restrict__ wtg,
                                            u16* __restrict__ s2g) {
  __shared__ union {
    alignas(16) u16 VT[128][128]; // V natural [s][i], swizzled granules (kvs phase A/B)
    alignas(16) u16 KT[128][136]; // Kb^T swizzled / S^T staging (kvs phase C); omega^T + sin^2 (proj)
  } sm;
  int bid = blockIdx.x, t = threadIdx.x;
  int lane = t & 63, quad = lane >> 4, nl = lane & 15, w = t >> 6;
  const float invL = 1.0f / 2048.0f;
  if (bid >= 512) { // ---- proj body: 128 rows per block
    int pb = bid - 512;
    int m = pb & 15, h = (pb >> 4) & 7, n = pb >> 7;
    int l0 = m << 7, nh = (n << 3) + h;
    for (int idx = t; idx < 2048; idx += 512) { // stage omega^T[h] (plain layout, as k_qfeat)
      int j = idx >> 4, cs = (idx & 15) << 3;
      *(s16x8*)&sm.KT[j][cs] = *(const s16x8*)(wtg + ((size_t)(h * 128 + j)) * 128 + cs);
    }
    __syncthreads();
    f32x4 z4 = {0.f, 0.f, 0.f, 0.f};
    f32x4 acc[8];
#pragma unroll
    for (int i = 0; i < 8; i++) acc[i] = z4;
    int arow = l0 + (w << 4) + nl;
    for (int ks = 0; ks < 4; ks++) {
      int k0 = (ks << 5) + (quad << 3);
      const float* ap = q2g + (((size_t)(n * Ln + arow) * 8 + h) << 7) + k0;
      s16x8 av = pack8(*(const f32x4*)ap, *(const f32x4*)(ap + 4));
#pragma unroll
      for (int ct = 0; ct < 8; ct++) {
        s16x8 bv = *(const s16x8*)&sm.KT[(ct << 4) + nl][k0];
        acc[ct] = __builtin_amdgcn_mfma_f32_16x16x32_bf16(av, bv, acc[ct], 0, 0, 0);
      }
    }
    __syncthreads();
    { // sin^2(proj) -> KT rows 0..127 (bf16, same f2b as k_qfeat's LDS round trip)
      int lbase = (w << 4) + (quad << 2);
#pragma unroll
      for (int ct = 0; ct < 8; ct++) {
        int j = (ct << 4) + nl;
#pragma unroll
        for (int r = 0; r < 4; r++) {
          float sp = __sinf(acc[ct][r]);
          sm.KT[lbase + r][j] = f2b(sp * sp);
        }
      }
    }
    __syncthreads();
    for (int idx = t; idx < 2048; idx += 512) { // stream s2 out (contiguous 32KB per block)
      int row = idx >> 4, g = (idx & 15) << 3;
      *(s16x8*)(s2g + ((size_t)(nh * Ln + l0 + row)) * 128 + g) = *(const s16x8*)&sm.KT[row][g];
    }
    return;
  }
  // ---- k_kvs body (R11 verbatim)
  int c = bid & 15, h = (bid >> 4) & 7, n = bid >> 7;
  int l0 = c << 7, nh = (n << 3) + h;
  int gcol = t & 31, cs = gcol << 2;          // column quad fixed per thread
  f32x4 osv = *(const f32x4*)(osum + h * 128 + cs);
  // phase A: features + kb3 direct stores + VT build
#pragma unroll
  for (int it = 0; it < 8; it++) {
    int rr = (it << 4) + (t >> 5);            // row in chunk 0..127
    int l = l0 + rr;
    size_t gb = (((size_t)(n * Ln + l) * 8 + h) << 7) + cs;
    f32x4 kv = *(const f32x4*)(kg + gb);
    f32x4 vv = *(const f32x4*)(vg + gb);
    float klv = klg[n * Ln + l];
    float tb = (float)l * invL;
    u16 r0[4], r1[4], r2[4];
#pragma unroll
    for (int e = 0; e < 4; e++) {
      float kf = (kv[e] > 0.f ? kv[e] + 1.f : __expf(kv[e])) * klv;
      float tt = tb * osv[e];
      float s, cc; __sincosf(tt, &s, &cc);
      r0[e] = f2b(kf * cc * cc);
      r1[e] = f2b(kf * s * s);
      r2[e] = f2b(kf * s * cc);
    }
    int gs = (gcol ^ (rr >> 3)) << 2;         // swizzled granule (4 u16)
    *(s16x4*)&sm.VT[rr][gs] = (s16x4){(short)f2b(vv[0]), (short)f2b(vv[1]),
                                      (short)f2b(vv[2]), (short)f2b(vv[3])};
    size_t nb = ((size_t)nh * Ln + l) * 128 + cs;
    *(s16x4*)(kb3 + nb)          = (s16x4){(short)r0[0], (short)r0[1], (short)r0[2], (short)r0[3]};
    *(s16x4*)(kb3 + NHLD + nb)   = (s16x4){(short)r1[0], (short)r1[1], (short)r1[2], (short)r1[3]};
    *(s16x4*)(kb3 + 2*NHLD + nb) = (s16x4){(short)r2[0], (short)r2[1], (short)r2[2], (short)r2[3]};
  }
  __syncthreads();
  // phase B: stream V^T chunk out (contiguous 32KB, full-line writes)
  size_t bv = ((size_t)(nh * 16 + c)) << 14;
  for (int idx = t; idx < 2048; idx += 512) {
    int i = idx >> 4, o = idx & 15;
    int gp = (((i >> 2) ^ o) << 2) + (i & 3);
    s16x8 v1;
#pragma unroll
    for (int u = 0; u < 8; u++) v1[u] = (short)sm.VT[(o << 3) + u][gp];
    *(s16x8*)(vt + bv + (((size_t)i) << 7) + (o << 3)) = v1;
  }
  // phase C: per-branch chunk-S^T (operands L2-hot)
  int arow = (w << 4) + nl;                   // j row, 8 waves x 16 = 128
  const u16* vchunk = vt + bv;
  for (int b = 0; b < 3; b++) {
    int bnh = b * 32 + nh;
    const u16* kb = kb3 + (size_t)b * NHLD + ((size_t)nh * Ln + l0) * 128;
    __syncthreads();                          // VT reads / prev sct stream done before KT overwrite
    for (int idx = t; idx < 2048; idx += 512) {
      int s = idx >> 4, io = idx & 15;        // natural row s, i-octet io
      s16x8 v = *(const s16x8*)(kb + (((size_t)s) << 7) + (io << 3)); // L2-hot (own writes)
      int cp = s ^ ((io & 7) << 3);           // swizzled phys column
#pragma unroll
      for (int j = 0; j < 8; j++) sm.KT[(io << 3) + j][cp] = (u16)(short)v[j];
    }
    __syncthreads();
    f32x4 z4 = {0.f, 0.f, 0.f, 0.f};
    f32x4 acc[8];
#pragma unroll
    for (int i = 0; i < 8; i++) acc[i] = z4;
    for (int ks = 0; ks < 4; ks++) {
      int k0 = (ks << 5) + (quad << 3);
      s16x8 av = *(const s16x8*)(vchunk + (((size_t)arow) << 7) + k0); // L2-hot
#pragma unroll
      for (int ct = 0; ct < 8; ct++) {
        int r = (ct << 4) + nl;
        int koff = k0 ^ (((r >> 3) & 7) << 3); // unswizzle octet
        s16x8 bvv = *(const s16x8*)&sm.KT[r][koff];
        acc[ct] = __builtin_amdgcn_mfma_f32_16x16x32_bf16(av, bvv, acc[ct], 0, 0, 0);
      }
    }
    if (t < 128) { // ksum[i] = row-sum of Kb^T row i (swizzle-aware octet reads)
      float s = 0.f;
      int sw = ((t >> 3) & 7) << 3;
#pragma unroll 4
      for (int g = 0; g < 128; g += 8) {
        s16x8 v = *(const s16x8*)&sm.KT[t][g ^ sw];
#pragma unroll
        for (int e = 0; e < 8; e++) s += b2f((u16)v[e]);
      }
      ksum[(size_t)(bnh * 16 + c) * 128 + t] = s;
    }
    __syncthreads();
    { // C-layout -> KT (as S^T[j][i], plain layout)
      int lbase = (w << 4) + (quad << 2);
#pragma unroll
      for (int ct = 0; ct < 8; ct++) {
        int i = (ct << 4) + nl;
#pragma unroll
        for (int r = 0; r < 4; r++) sm.KT[lbase + r][i] = f2b(acc[ct][r]);
      }
    }
    __syncthreads();
    size_t sbase = ((size_t)(bnh * 16 + c)) << 14;
    for (int idx = t; idx < 2048; idx += 512) {
      int jr = idx >> 4, g = (idx & 15) << 3;
      *(s16x8*)(sct + sbase + ((size_t)jr << 7) + g) = *(const s16x8*)&sm.KT[jr][g];
    }
  }
}

// ---------------- P1k: ksum exclusive prefix over chunks (kqm's only prefix dependency)
__global__ __launch_bounds__(256) void p1k(float* __restrict__ ksum) {
  int m2 = blockIdx.x * 256 + threadIdx.x;  // 0..12287
  int i = m2 & 127, bnh = m2 >> 7;
  size_t base = (size_t)bnh * 2048 + i;
  float acc = 0.f;
  for (int c = 0; c < 16; c++) {
    size_t a = base + (size_t)c * 128;
    float v = ksum[a];
    ksum[a] = acc;
    acc += v;
  }
}

// ---------------- KQM: blocks 0..1023 = Q features final pass (s2 from global; no MFMA);
// blocks 1024..1791 = sct exclusive prefix (verbatim). Both streaming-only now.
__global__ __launch_bounds__(256) void kqm(const float* __restrict__ qg, const float* __restrict__ osum,
                                           const float* __restrict__ kspre, const u16* __restrict__ s2g,
                                           u16* __restrict__ qb3, float* __restrict__ zintg,
                                           u16* __restrict__ sct) {
  __shared__ float osb[128];
  int bid = blockIdx.x, t = threadIdx.x;
  if (bid >= 1024) { // ---- sct exclusive prefix over chunks (verbatim)
    int tid = (bid - 1024) * 256 + t;  // 0..196607
    int bnh = tid >> 11, rem = tid & 2047;
    size_t base = ((size_t)bnh << 18) + ((size_t)rem << 3);
    float acc[8] = {0.f, 0.f, 0.f, 0.f, 0.f, 0.f, 0.f, 0.f};
    for (int c = 0; c < 16; c++) {
      size_t a = base + ((size_t)c << 14);
      s16x8 v = *(const s16x8*)(sct + a);
      s16x8 o;
#pragma unroll
      for (int e = 0; e < 8; e++) { o[e] = (short)f2b(acc[e]); acc[e] += b2f((u16)v[e]); }
      *(s16x8*)(sct + a) = o;
    }
    return;
  }
  // ---- Q features final pass (R11 k_qfeat tail, s2v from global instead of LDS)
  int m = bid & 31, h = (bid >> 5) & 7, n = bid >> 8;
  int l0 = m << 6, c = m >> 1, nh = (n << 3) + h;
  int nl = t & 15;
  if (t < 128) osb[t] = osum[h * 128 + t];
  __syncthreads();
  const float invL = 1.0f / 2048.0f;
  for (int idx = t; idx < 1024; idx += 256) {
    int l = idx >> 4, j0 = (idx & 15) << 3, gl = l0 + l;
    s16x8 s2v = *(const s16x8*)(s2g + ((size_t)nh * Ln + gl) * 128 + j0); // L3-hot
    const float* qp = qg + (((size_t)(n * Ln + gl) * 8 + h) << 7) + j0;
    f32x4 qa = *(const f32x4*)qp, qbv = *(const f32x4*)(qp + 4);
    size_t kbb = ((size_t)nh * 16 + c) * 128 + j0;
    f32x4 kp0a = *(const f32x4*)(kspre + kbb),           kp0b = *(const f32x4*)(kspre + kbb + 4);
    f32x4 kp1a = *(const f32x4*)(kspre + kbb + KSB),     kp1b = *(const f32x4*)(kspre + kbb + KSB + 4);
    f32x4 kp2a = *(const f32x4*)(kspre + kbb + 2 * KSB), kp2b = *(const f32x4*)(kspre + kbb + 2 * KSB + 4);
    s16x8 o0, o1, o2;
    float z = 0.f;
    float tb = (float)gl * invL;
#pragma unroll
    for (int e = 0; e < 8; e++) {
      float s2p = b2f((u16)s2v[e]);
      float qv = (e < 4) ? qa[e] : qbv[e - 4];
      float f = qv > 0.f ? qv + 1.f : __expf(qv);
      float Qt = s2p * f;
      float tt = tb * osb[j0 + e];
      float s, cc; __sincosf(tt, &s, &cc);
      float v0 = Qt * s * s, v1 = Qt * cc * cc, v2 = -2.f * Qt * s * cc;
      float k0v = (e < 4) ? kp0a[e] : kp0b[e - 4];
      float k1v = (e < 4) ? kp1a[e] : kp1b[e - 4];
      float k2v = (e < 4) ? kp2a[e] : kp2b[e - 4];
      z += v0 * k0v + v1 * k1v + v2 * k2v;
      o0[e] = (short)f2b(v0); o1[e] = (short)f2b(v1); o2[e] = (short)f2b(v2);
    }
    size_t base = ((size_t)nh * Ln + gl) * 128 + j0;
    *(s16x8*)(qb3 + base)            = o0;
    *(s16x8*)(qb3 + base + NHLD)     = o1;
    *(s16x8*)(qb3 + base + 2 * NHLD) = o2;
    z += __shfl_xor(z, 1); z += __shfl_xor(z, 2);
    z += __shfl_xor(z, 4); z += __shfl_xor(z, 8);
    if (nl == 0) zintg[(size_t)nh * Ln + gl] = z;
  }
}

// ---------------- P3: octet-XOR-swizzled stride-128 tiles, A-fragments hoisted pre-barrier.
// (R11 verbatim)
__global__ __launch_bounds__(512, 4) void p3(const u16* __restrict__ qb3, const u16* __restrict__ kb3,
                                             const u16* __restrict__ vtg, const u16* __restrict__ sct,
                                             const float* __restrict__ zintg, float* __restrict__ outg) {
  __shared__ union {
    struct { alignas(16) u16 T0[128][128]; alignas(16) u16 T1[128][128]; } s;
    alignas(16) float O[128][132];
  } sm;
  int bid = blockIdx.x, t = threadIdx.x;
  int c = bid & 15, h = (bid >> 4) & 7, n = bid >> 7;
  int l0c = c << 7, nh = (n << 3) + h;
  int lane = t & 63, quad = lane >> 4, nl = lane & 15, w = t >> 6;
  f32x4 z4 = {0.f, 0.f, 0.f, 0.f};
  f32x4 accP[8], accO[8];
#pragma unroll
  for (int i = 0; i < 8; i++) { accP[i] = z4; accO[i] = z4; }
  int arow = l0c + (w << 4) + nl;
  for (int b = 0; b < 3; b++) {
    int bnh = b * 32 + nh;
    __syncthreads();
    for (int idx = t; idx < 2048; idx += 512) { // T0 <- Kb chunk [s][i], swizzled octets
      int s = idx >> 4;
      int co = (((idx & 15) ^ (s & 7)) << 3);
      *(s16x8*)&sm.s.T0[s][co] = *(const s16x8*)(kb3 + (((size_t)bnh * Ln + l0c + s) << 7) + ((idx & 15) << 3));
    }
    size_t sbase = ((size_t)(bnh * 16 + c)) << 14;
    for (int idx = t; idx < 2048; idx += 512) { // T1 <- Sprefix^T [j][i], swizzled octets
      int j = idx >> 4;
      int co = (((idx & 15) ^ (j & 7)) << 3);
      *(s16x8*)&sm.s.T1[j][co] = *(const s16x8*)(sct + sbase + ((size_t)j << 7) + ((idx & 15) << 3));
    }
    s16x8 av[4]; // A-fragments issued before the barrier (latency hidden under staging)
#pragma unroll
    for (int ks = 0; ks < 4; ks++)
      av[ks] = *(const s16x8*)(qb3 + (((size_t)bnh * Ln + arow) << 7) + (ks << 5) + (quad << 3));
    __syncthreads();
    for (int ks = 0; ks < 4; ks++) {
      int k0 = (ks << 5) + (quad << 3);
#pragma unroll
      for (int ct = 0; ct < 8; ct++) {
        int r = (ct << 4) + nl;
        int koff = k0 ^ ((r & 7) << 3);       // unswizzle
        s16x8 bv0 = *(const s16x8*)&sm.s.T0[r][koff];
        accP[ct] = __builtin_amdgcn_mfma_f32_16x16x32_bf16(av[ks], bv0, accP[ct], 0, 0, 0);
        s16x8 bv1 = *(const s16x8*)&sm.s.T1[r][koff];
        accO[ct] = __builtin_amdgcn_mfma_f32_16x16x32_bf16(av[ks], bv1, accO[ct], 0, 0, 0);
      }
    }
  }
  __syncthreads();
  // masked P -> T0 as P[l][s] (bf16, swizzled) + register row-sums; stage T1 <- V^T [j][sc]
  float zP[4] = {0.f, 0.f, 0.f, 0.f};
  int lbase = (w << 4) + (quad << 2);
#pragma unroll
  for (int ct = 0; ct < 8; ct++) {
    int ss = (ct << 4) + nl;
#pragma unroll
    for (int r = 0; r < 4; r++) {
      int lr = lbase + r;
      float pv = (ss <= lr) ? accP[ct][r] : 0.f;
      zP[r] += pv;
      sm.s.T0[lr][ss ^ ((lr & 7) << 3)] = f2b(pv);
    }
  }
#pragma unroll
  for (int mteam = 1; mteam <= 8; mteam <<= 1) {
#pragma unroll
    for (int r = 0; r < 4; r++) zP[r] += __shfl_xor(zP[r], mteam);
  }
  size_t vbase = ((size_t)(nh * 16 + c)) << 14;
  for (int idx = t; idx < 2048; idx += 512) { // T1 <- V^T chunk (linear 32KB stream), swizzled
    int j = idx >> 4;
    int co = (((idx & 15) ^ (j & 7)) << 3);
    *(s16x8*)&sm.s.T1[j][co] = *(const s16x8*)(vtg + vbase + ((size_t)idx << 3));
  }
  float zf[4];
#pragma unroll
  for (int r = 0; r < 4; r++)
    zf[r] = zintg[(size_t)nh * Ln + l0c + lbase + r] + zP[r] + 1e-6f;
  __syncthreads();
  // intra: A = masked P (T0 rows l, k=s), B = V^T (T1 rows j, k=s)
  for (int ks = 0; ks < 4; ks++) {
    int k0 = (ks << 5) + (quad << 3);
    int rw = (w << 4) + nl;
    s16x8 pav = *(const s16x8*)&sm.s.T0[rw][k0 ^ ((rw & 7) << 3)];
#pragma unroll
    for (int ct = 0; ct < 8; ct++) {
      int r = (ct << 4) + nl;
      s16x8 vv = *(const s16x8*)&sm.s.T1[r][k0 ^ ((r & 7) << 3)];
      accO[ct] = __builtin_amdgcn_mfma_f32_16x16x32_bf16(pav, vv, accO[ct], 0, 0, 0);
    }
  }
  __syncthreads();
  // divided result -> fp32 LDS overlay (T0/T1 dead now)
#pragma unroll
  for (int ct = 0; ct < 8; ct++) {
    int j = (ct << 4) + nl;
#pragma unroll
    for (int r = 0; r < 4; r++) sm.O[lbase + r][j] = accO[ct][r] / zf[r];
  }
  __syncthreads();
  for (int idx = t; idx < 4096; idx += 512) { // full 512B-row coalesced stores
    int l = idx >> 5, g = (idx & 31) << 2;
    *(f32x4*)(outg + (((size_t)(n * Ln + l0c + l) * 8 + h) << 7) + g) = *(const f32x4*)&sm.O[l][g];
  }
}

extern "C" void kernel_launch(void* const* d_in, const int* in_sizes, int n_in,
                              void* d_out, int out_size, void* d_ws, size_t ws_size,
                              hipStream_t stream) {
  (void)in_sizes; (void)n_in; (void)out_size; (void)ws_size;
  const float* q   = (const float*)d_in[0];
  const float* q2  = (const float*)d_in[1];
  const float* kk  = (const float*)d_in[2];
  const float* vv  = (const float*)d_in[3];
  const float* kl  = (const float*)d_in[4];
  const float* om  = (const float*)d_in[5];
  float* out = (float*)d_out;

  // workspace carve (bf16 region then fp32 region) — ~187 MB
  u16* W     = (u16*)d_ws;
  u16* qb3   = W;                 // 3*NHLD
  u16* kb3   = W + 3 * NHLD;      // 3*NHLD (naturals; kvsp transposes in-block, L2-hot)
  u16* vt    = W + 6 * NHLD;      // NHLD   (chunk-blocked [nh][c][i][sc])
  u16* sct   = W + 7 * NHLD;      // 3*NHLD (chunk sums -> exclusive prefix, in place)
  u16* s2    = W + 10 * NHLD;     // NHLD   (sin^2(proj) bf16)
  u16* wt    = W + 11 * NHLD;     // 131072 (omega^T bf16)
  float* ks  = (float*)(W + 11 * NHLD + 131072); // 196608 f32 (chunk Ksum -> prefix)
  float* osm = ks + 196608;       // 1024 f32
  float* zin = osm + 1024;        // 65536 f32 (Z_inter)

  k_omega <<<8,    256, 0, stream>>>(om, wt, osm);
  kvsp    <<<1024, 512, 0, stream>>>(kk, vv, kl, osm, kb3, vt, sct, ks, q2, wt, s2);
  p1k     <<<48,   256, 0, stream>>>(ks);
  kqm     <<<1792, 256, 0, stream>>>(q, osm, ks, s2, qb3, zin, sct);
  p3      <<<512,  512, 0, stream>>>(qb3, kb3, vt, sct, zin, out);
}

// Round 13
// 269.398 us; speedup vs baseline: 1.0163x; 1.0163x over previous
//
#include <hip/hip_runtime.h>

// CausalLinearRelativeAttention — chunked 3-branch causal linear attention, bf16 MFMA.
// N=4, L=2048, H=8, D=Dv=128, chunk C=128, T=16 chunks, 3 branches (coeff -2 folded into Qb2).
// R8: dropped kbt3. R11: k_kvfeat+p1a fused (k_kvs). R15: sct-prefix merged into kqm = 266.6us.
// R16: proj-into-kvs overlap REGRESSED (+50MB into a BW-saturated window = +17us; lever spent).
// R17: revert to R15 + one cut: k_kvs phase C stages KT from phase-A REGISTERS (48 VGPRs hold
//      the packed bf16 features) instead of re-reading kb3 (drops 12 b128 global loads/thread
//      from the critical path; bit-identical mapping incl. octet swizzle).

typedef float f32x4 __attribute__((ext_vector_type(4)));
typedef short s16x8 __attribute__((ext_vector_type(8)));
typedef short s16x4 __attribute__((ext_vector_type(4)));
typedef unsigned short u16;

static constexpr int    Ln   = 2048;
static constexpr size_t NHLD = (size_t)32 * 2048 * 128; // per-branch feature elems = 8,388,608
static constexpr size_t KSB  = (size_t)32 * 16 * 128;   // kspre per-branch stride = 65536

__device__ __forceinline__ float b2f(u16 s) {
  union { unsigned u; float f; } x; x.u = ((unsigned)s) << 16; return x.f;
}
__device__ __forceinline__ u16 f2b(float f) {
  union { float f; unsigned u; } x; x.f = f;
  unsigned r = x.u + 0x7fffu + ((x.u >> 16) & 1u);
  return (u16)(r >> 16);
}
__device__ __forceinline__ s16x8 pack8(f32x4 a, f32x4 b) {
  s16x8 r;
  r[0] = (short)f2b(a[0]); r[1] = (short)f2b(a[1]); r[2] = (short)f2b(a[2]); r[3] = (short)f2b(a[3]);
  r[4] = (short)f2b(b[0]); r[5] = (short)f2b(b[1]); r[6] = (short)f2b(b[2]); r[7] = (short)f2b(b[3]);
  return r;
}

// ---------------------------------------------------------------- K0: omega^T (bf16) + column sums
__global__ __launch_bounds__(256) void k_omega(const float* __restrict__ om,
                                               u16* __restrict__ wt, float* __restrict__ osum) {
  __shared__ alignas(16) u16 T[128][136];
  int h = blockIdx.x, t = threadIdx.x;
  for (int idx = t; idx < 128 * 32; idx += 256) {
    int i = idx >> 5, cs = (idx & 31) << 2;
    f32x4 vv = *(const f32x4*)(om + ((size_t)(h * 128 + i)) * 128 + cs);
    T[i][cs + 0] = f2b(vv[0]); T[i][cs + 1] = f2b(vv[1]);
    T[i][cs + 2] = f2b(vv[2]); T[i][cs + 3] = f2b(vv[3]);
  }
  if (t < 128) { // exact fp32 column sums (coalesced per row)
    float acc = 0.f;
    for (int i = 0; i < 128; i++) acc += om[((size_t)(h * 128 + i)) * 128 + t];
    osum[h * 128 + t] = acc;
  }
  __syncthreads();
  { // transposed write: wt[h][j][i] = omega[h][i][j]
    int j = t >> 1, lh = (t & 1) << 6;
    s16x8* dst = (s16x8*)(wt + ((size_t)(h * 128 + j)) * 128 + lh);
    for (int u = 0; u < 8; u++) {
      s16x8 pv;
#pragma unroll
      for (int e = 0; e < 8; e++) pv[e] = (short)T[lh + u * 8 + e][j];
      dst[u] = pv;
    }
  }
}

// ---------------------- K1+P1a fused (k_kvs): one block per (n,h,c), 512 threads.
// Phase A: features -> kb3 direct + VT build; packed feature bits KEPT in registers.
// Phase B: stream vt out. Phase C (x3 branches): KT staged from REGISTERS (no kb3 re-read),
//   S^T MFMA (A = vt rows, L2-hot), ksum rowsum, restage S^T, stream sct out.
__global__ __launch_bounds__(512) void k_kvs(const float* __restrict__ kg, const float* __restrict__ vg,
                                             const float* __restrict__ klg, const float* __restrict__ osum,
                                             u16* __restrict__ kb3, u16* __restrict__ vt,
                                             u16* __restrict__ sct, float* __restrict__ ksum) {
  __shared__ union {
    alignas(16) u16 VT[128][128]; // V natural [s][i], swizzled granules (phase A/B)
    alignas(16) u16 KT[128][136]; // Kb^T [i][s] swizzled; then S^T staging (phase C)
  } sm;
  int bid = blockIdx.x, t = threadIdx.x;
  int c = bid & 15, h = (bid >> 4) & 7, n = bid >> 7;
  int l0 = c << 7, nh = (n << 3) + h;
  const float invL = 1.0f / 2048.0f;
  int gcol = t & 31, cs = gcol << 2;          // column quad fixed per thread
  f32x4 osv = *(const f32x4*)(osum + h * 128 + cs);
  unsigned rp0[8][2], rp1[8][2], rp2[8][2];   // packed bf16 features, kept A -> C
  // ---- phase A: features + kb3 direct stores + VT build
#pragma unroll
  for (int it = 0; it < 8; it++) {
    int rr = (it << 4) + (t >> 5);            // row in chunk 0..127
    int l = l0 + rr;
    size_t gb = (((size_t)(n * Ln + l) * 8 + h) << 7) + cs;
    f32x4 kv = *(const f32x4*)(kg + gb);
    f32x4 vv = *(const f32x4*)(vg + gb);
    float klv = klg[n * Ln + l];
    float tb = (float)l * invL;
    u16 r0[4], r1[4], r2[4];
#pragma unroll
    for (int e = 0; e < 4; e++) {
      float kf = (kv[e] > 0.f ? kv[e] + 1.f : __expf(kv[e])) * klv;
      float tt = tb * osv[e];
      float s, cc; __sincosf(tt, &s, &cc);
      r0[e] = f2b(kf * cc * cc);
      r1[e] = f2b(kf * s * s);
      r2[e] = f2b(kf * s * cc);
    }
    rp0[it][0] = (unsigned)r0[0] | ((unsigned)r0[1] << 16);
    rp0[it][1] = (unsigned)r0[2] | ((unsigned)r0[3] << 16);
    rp1[it][0] = (unsigned)r1[0] | ((unsigned)r1[1] << 16);
    rp1[it][1] = (unsigned)r1[2] | ((unsigned)r1[3] << 16);
    rp2[it][0] = (unsigned)r2[0] | ((unsigned)r2[1] << 16);
    rp2[it][1] = (unsigned)r2[2] | ((unsigned)r2[3] << 16);
    int gs = (gcol ^ (rr >> 3)) << 2;         // swizzled granule (4 u16)
    *(s16x4*)&sm.VT[rr][gs] = (s16x4){(short)f2b(vv[0]), (short)f2b(vv[1]),
                                      (short)f2b(vv[2]), (short)f2b(vv[3])};
    size_t nb = ((size_t)nh * Ln + l) * 128 + cs;
    *(s16x4*)(kb3 + nb)          = (s16x4){(short)r0[0], (short)r0[1], (short)r0[2], (short)r0[3]};
    *(s16x4*)(kb3 + NHLD + nb)   = (s16x4){(short)r1[0], (short)r1[1], (short)r1[2], (short)r1[3]};
    *(s16x4*)(kb3 + 2*NHLD + nb) = (s16x4){(short)r2[0], (short)r2[1], (short)r2[2], (short)r2[3]};
  }
  __syncthreads();
  // ---- phase B: stream V^T chunk out (contiguous 32KB, full-line writes)
  size_t bv = ((size_t)(nh * 16 + c)) << 14;
  for (int idx = t; idx < 2048; idx += 512) {
    int i = idx >> 4, o = idx & 15;
    int gp = (((i >> 2) ^ o) << 2) + (i & 3);
    s16x8 v1;
#pragma unroll
    for (int u = 0; u < 8; u++) v1[u] = (short)sm.VT[(o << 3) + u][gp];
    *(s16x8*)(vt + bv + (((size_t)i) << 7) + (o << 3)) = v1;
  }
  // ---- phase C: per-branch chunk-S^T (KT from registers; A-operand vt L2-hot)
  int lane = t & 63, quad = lane >> 4, nl = lane & 15, w = t >> 6;
  int arow = (w << 4) + nl;                   // j row, 8 waves x 16 = 128
  const u16* vchunk = vt + bv;
  int srow = t >> 5;                          // phase-A row base (matches rr)
  int octsw = ((cs >> 3) & 7) << 3;           // octet-swizzle term, constant per thread
  for (int b = 0; b < 3; b++) {
    int bnh = b * 32 + nh;
    __syncthreads();                          // VT reads / prev sct stream done before KT overwrite
#pragma unroll
    for (int it = 0; it < 8; it++) {          // KT[i][s^swz] <- register bits (no global reads)
      int s0 = (it << 4) + srow;
      int cp = s0 ^ octsw;
      unsigned v0 = (b == 0) ? rp0[it][0] : (b == 1) ? rp1[it][0] : rp2[it][0];
      unsigned v1 = (b == 0) ? rp0[it][1] : (b == 1) ? rp1[it][1] : rp2[it][1];
      sm.KT[cs + 0][cp] = (u16)(v0 & 0xffffu);
      sm.KT[cs + 1][cp] = (u16)(v0 >> 16);
      sm.KT[cs + 2][cp] = (u16)(v1 & 0xffffu);
      sm.KT[cs + 3][cp] = (u16)(v1 >> 16);
    }
    __syncthreads();
    f32x4 z4 = {0.f, 0.f, 0.f, 0.f};
    f32x4 acc[8];
#pragma unroll
    for (int i = 0; i < 8; i++) acc[i] = z4;
    for (int ks = 0; ks < 4; ks++) {
      int k0 = (ks << 5) + (quad << 3);
      s16x8 av = *(const s16x8*)(vchunk + (((size_t)arow) << 7) + k0); // L2-hot
#pragma unroll
      for (int ct = 0; ct < 8; ct++) {
        int r = (ct << 4) + nl;
        int koff = k0 ^ (((r >> 3) & 7) << 3); // unswizzle octet
        s16x8 bvv = *(const s16x8*)&sm.KT[r][koff];
        acc[ct] = __builtin_amdgcn_mfma_f32_16x16x32_bf16(av, bvv, acc[ct], 0, 0, 0);
      }
    }
    if (t < 128) { // ksum[i] = row-sum of Kb^T row i (swizzle-aware octet reads)
      float s = 0.f;
      int sw = ((t >> 3) & 7) << 3;
#pragma unroll 4
      for (int g = 0; g < 128; g += 8) {
        s16x8 v = *(const s16x8*)&sm.KT[t][g ^ sw];
#pragma unroll
        for (int e = 0; e < 8; e++) s += b2f((u16)v[e]);
      }
      ksum[(size_t)(bnh * 16 + c) * 128 + t] = s;
    }
    __syncthreads();
    { // C-layout -> KT (as S^T[j][i], plain layout)
      int lbase = (w << 4) + (quad << 2);
#pragma unroll
      for (int ct = 0; ct < 8; ct++) {
        int i = (ct << 4) + nl;
#pragma unroll
        for (int r = 0; r < 4; r++) sm.KT[lbase + r][i] = f2b(acc[ct][r]);
      }
    }
    __syncthreads();
    size_t sbase = ((size_t)(bnh * 16 + c)) << 14;
    for (int idx = t; idx < 2048; idx += 512) {
      int jr = idx >> 4, g = (idx & 15) << 3;
      *(s16x8*)(sct + sbase + ((size_t)jr << 7) + g) = *(const s16x8*)&sm.KT[jr][g];
    }
  }
}

// ---------------- P1k: ksum exclusive prefix over chunks (kqm's only prefix dependency)
__global__ __launch_bounds__(256) void p1k(float* __restrict__ ksum) {
  int m2 = blockIdx.x * 256 + threadIdx.x;  // 0..12287
  int i = m2 & 127, bnh = m2 >> 7;
  size_t base = (size_t)bnh * 2048 + i;
  float acc = 0.f;
  for (int c = 0; c < 16; c++) {
    size_t a = base + (size_t)c * 128;
    float v = ksum[a];
    ksum[a] = acc;
    acc += v;
  }
}

// ---------------- KQM: merged k_qfeat (blocks 0..1023) + sct exclusive prefix (blocks 1024..1791).
__global__ __launch_bounds__(256, 2) void kqm(const float* __restrict__ q2g, const float* __restrict__ qg,
                                              const u16* __restrict__ wt, const float* __restrict__ osum,
                                              const float* __restrict__ kspre,
                                              u16* __restrict__ qb3, float* __restrict__ zintg,
                                              u16* __restrict__ sct) {
  __shared__ alignas(16) u16 B[128][136]; // omega^T[h]; later reused rows 0..63 for sin^2(proj)
  __shared__ float osb[128];
  int bid = blockIdx.x, t = threadIdx.x;
  if (bid >= 1024) { // ---- sct exclusive prefix over chunks (p1b body, verbatim)
    int tid = (bid - 1024) * 256 + t;  // 0..196607
    int bnh = tid >> 11, rem = tid & 2047;
    size_t base = ((size_t)bnh << 18) + ((size_t)rem << 3);
    float acc[8] = {0.f, 0.f, 0.f, 0.f, 0.f, 0.f, 0.f, 0.f};
    for (int c = 0; c < 16; c++) {
      size_t a = base + ((size_t)c << 14);
      s16x8 v = *(const s16x8*)(sct + a);
      s16x8 o;
#pragma unroll
      for (int e = 0; e < 8; e++) { o[e] = (short)f2b(acc[e]); acc[e] += b2f((u16)v[e]); }
      *(s16x8*)(sct + a) = o;
    }
    return;
  }
  // ---- k_qfeat body (R11 verbatim)
  int m = bid & 31, h = (bid >> 5) & 7, n = bid >> 8;
  int l0 = m << 6, c = m >> 1, nh = (n << 3) + h;
  if (t < 128) osb[t] = osum[h * 128 + t];
  for (int idx = t; idx < 2048; idx += 256) {
    int j = idx >> 4, cs = (idx & 15) << 3;
    *(s16x8*)&B[j][cs] = *(const s16x8*)(wt + ((size_t)(h * 128 + j)) * 128 + cs);
  }
  __syncthreads();
  int lane = t & 63, quad = lane >> 4, nl = lane & 15, w = t >> 6;
  f32x4 z4 = {0.f, 0.f, 0.f, 0.f};
  f32x4 acc[8];
#pragma unroll
  for (int i = 0; i < 8; i++) acc[i] = z4;
  int arow = l0 + (w << 4) + nl;
  for (int ks = 0; ks < 4; ks++) {
    int k0 = (ks << 5) + (quad << 3);
    const float* ap = q2g + (((size_t)(n * Ln + arow) * 8 + h) << 7) + k0;
    s16x8 av = pack8(*(const f32x4*)ap, *(const f32x4*)(ap + 4));
#pragma unroll
    for (int ct = 0; ct < 8; ct++) {
      s16x8 bv = *(const s16x8*)&B[(ct << 4) + nl][k0];
      acc[ct] = __builtin_amdgcn_mfma_f32_16x16x32_bf16(av, bv, acc[ct], 0, 0, 0);
    }
  }
  __syncthreads();
  { // sin^2(proj) -> B rows 0..63
    int lbase = (w << 4) + (quad << 2);
#pragma unroll
    for (int ct = 0; ct < 8; ct++) {
      int j = (ct << 4) + nl;
#pragma unroll
      for (int r = 0; r < 4; r++) {
        float sp = __sinf(acc[ct][r]);
        B[lbase + r][j] = f2b(sp * sp);
      }
    }
  }
  __syncthreads();
  const float invL = 1.0f / 2048.0f;
  for (int idx = t; idx < 1024; idx += 256) {
    int l = idx >> 4, j0 = (idx & 15) << 3, gl = l0 + l;
    s16x8 s2v = *(const s16x8*)&B[l][j0];
    const float* qp = qg + (((size_t)(n * Ln + gl) * 8 + h) << 7) + j0;
    f32x4 qa = *(const f32x4*)qp, qbv = *(const f32x4*)(qp + 4);
    size_t kbb = ((size_t)nh * 16 + c) * 128 + j0;
    f32x4 kp0a = *(const f32x4*)(kspre + kbb),           kp0b = *(const f32x4*)(kspre + kbb + 4);
    f32x4 kp1a = *(const f32x4*)(kspre + kbb + KSB),     kp1b = *(const f32x4*)(kspre + kbb + KSB + 4);
    f32x4 kp2a = *(const f32x4*)(kspre + kbb + 2 * KSB), kp2b = *(const f32x4*)(kspre + kbb + 2 * KSB + 4);
    s16x8 o0, o1, o2;
    float z = 0.f;
    float tb = (float)gl * invL;
#pragma unroll
    for (int e = 0; e < 8; e++) {
      float s2p = b2f((u16)s2v[e]);
      float qv = (e < 4) ? qa[e] : qbv[e - 4];
      float f = qv > 0.f ? qv + 1.f : __expf(qv);
      float Qt = s2p * f;
      float tt = tb * osb[j0 + e];
      float s, cc; __sincosf(tt, &s, &cc);
      float v0 = Qt * s * s, v1 = Qt * cc * cc, v2 = -2.f * Qt * s * cc;
      float k0v = (e < 4) ? kp0a[e] : kp0b[e - 4];
      float k1v = (e < 4) ? kp1a[e] : kp1b[e - 4];
      float k2v = (e < 4) ? kp2a[e] : kp2b[e - 4];
      z += v0 * k0v + v1 * k1v + v2 * k2v;
      o0[e] = (short)f2b(v0); o1[e] = (short)f2b(v1); o2[e] = (short)f2b(v2);
    }
    size_t base = ((size_t)nh * Ln + gl) * 128 + j0;
    *(s16x8*)(qb3 + base)            = o0;
    *(s16x8*)(qb3 + base + NHLD)     = o1;
    *(s16x8*)(qb3 + base + 2 * NHLD) = o2;
    z += __shfl_xor(z, 1); z += __shfl_xor(z, 2);
    z += __shfl_xor(z, 4); z += __shfl_xor(z, 8);
    if (nl == 0) zintg[(size_t)nh * Ln + gl] = z;
  }
}

// ---------------- P3: octet-XOR-swizzled stride-128 tiles, A-fragments hoisted pre-barrier.
// (R11 verbatim)
__global__ __launch_bounds__(512, 4) void p3(const u16* __restrict__ qb3, const u16* __restrict__ kb3,
                                             const u16* __restrict__ vtg, const u16* __restrict__ sct,
                                             const float* __restrict__ zintg, float* __restrict__ outg) {
  __shared__ union {
    struct { alignas(16) u16 T0[128][128]; alignas(16) u16 T1[128][128]; } s;
    alignas(16) float O[128][132];
  } sm;
  int bid = blockIdx.x, t = threadIdx.x;
  int c = bid & 15, h = (bid >> 4) & 7, n = bid >> 7;
  int l0c = c << 7, nh = (n << 3) + h;
  int lane = t & 63, quad = lane >> 4, nl = lane & 15, w = t >> 6;
  f32x4 z4 = {0.f, 0.f, 0.f, 0.f};
  f32x4 accP[8], accO[8];
#pragma unroll
  for (int i = 0; i < 8; i++) { accP[i] = z4; accO[i] = z4; }
  int arow = l0c + (w << 4) + nl;
  for (int b = 0; b < 3; b++) {
    int bnh = b * 32 + nh;
    __syncthreads();
    for (int idx = t; idx < 2048; idx += 512) { // T0 <- Kb chunk [s][i], swizzled octets
      int s = idx >> 4;
      int co = (((idx & 15) ^ (s & 7)) << 3);
      *(s16x8*)&sm.s.T0[s][co] = *(const s16x8*)(kb3 + (((size_t)bnh * Ln + l0c + s) << 7) + ((idx & 15) << 3));
    }
    size_t sbase = ((size_t)(bnh * 16 + c)) << 14;
    for (int idx = t; idx < 2048; idx += 512) { // T1 <- Sprefix^T [j][i], swizzled octets
      int j = idx >> 4;
      int co = (((idx & 15) ^ (j & 7)) << 3);
      *(s16x8*)&sm.s.T1[j][co] = *(const s16x8*)(sct + sbase + ((size_t)j << 7) + ((idx & 15) << 3));
    }
    s16x8 av[4]; // A-fragments issued before the barrier (latency hidden under staging)
#pragma unroll
    for (int ks = 0; ks < 4; ks++)
      av[ks] = *(const s16x8*)(qb3 + (((size_t)bnh * Ln + arow) << 7) + (ks << 5) + (quad << 3));
    __syncthreads();
    for (int ks = 0; ks < 4; ks++) {
      int k0 = (ks << 5) + (quad << 3);
#pragma unroll
      for (int ct = 0; ct < 8; ct++) {
        int r = (ct << 4) + nl;
        int koff = k0 ^ ((r & 7) << 3);       // unswizzle
        s16x8 bv0 = *(const s16x8*)&sm.s.T0[r][koff];
        accP[ct] = __builtin_amdgcn_mfma_f32_16x16x32_bf16(av[ks], bv0, accP[ct], 0, 0, 0);
        s16x8 bv1 = *(const s16x8*)&sm.s.T1[r][koff];
        accO[ct] = __builtin_amdgcn_mfma_f32_16x16x32_bf16(av[ks], bv1, accO[ct], 0, 0, 0);
      }
    }
  }
  __syncthreads();
  // masked P -> T0 as P[l][s] (bf16, swizzled) + register row-sums; stage T1 <- V^T [j][sc]
  float zP[4] = {0.f, 0.f, 0.f, 0.f};
  int lbase = (w << 4) + (quad << 2);
#pragma unroll
  for (int ct = 0; ct < 8; ct++) {
    int ss = (ct << 4) + nl;
#pragma unroll
    for (int r = 0; r < 4; r++) {
      int lr = lbase + r;
      float pv = (ss <= lr) ? accP[ct][r] : 0.f;
      zP[r] += pv;
      sm.s.T0[lr][ss ^ ((lr & 7) << 3)] = f2b(pv);
    }
  }
#pragma unroll
  for (int mteam = 1; mteam <= 8; mteam <<= 1) {
#pragma unroll
    for (int r = 0; r < 4; r++) zP[r] += __shfl_xor(zP[r], mteam);
  }
  size_t vbase = ((size_t)(nh * 16 + c)) << 14;
  for (int idx = t; idx < 2048; idx += 512) { // T1 <- V^T chunk (linear 32KB stream), swizzled
    int j = idx >> 4;
    int co = (((idx & 15) ^ (j & 7)) << 3);
    *(s16x8*)&sm.s.T1[j][co] = *(const s16x8*)(vtg + vbase + ((size_t)idx << 3));
  }
  float zf[4];
#pragma unroll
  for (int r = 0; r < 4; r++)
    zf[r] = zintg[(size_t)nh * Ln + l0c + lbase + r] + zP[r] + 1e-6f;
  __syncthreads();
  // intra: A = masked P (T0 rows l, k=s), B = V^T (T1 rows j, k=s)
  for (int ks = 0; ks < 4; ks++) {
    int k0 = (ks << 5) + (quad << 3);
    int rw = (w << 4) + nl;
    s16x8 pav = *(const s16x8*)&sm.s.T0[rw][k0 ^ ((rw & 7) << 3)];
#pragma unroll
    for (int ct = 0; ct < 8; ct++) {
      int r = (ct << 4) + nl;
      s16x8 vv = *(const s16x8*)&sm.s.T1[r][k0 ^ ((r & 7) << 3)];
      accO[ct] = __builtin_amdgcn_mfma_f32_16x16x32_bf16(pav, vv, accO[ct], 0, 0, 0);
    }
  }
  __syncthreads();
  // divided result -> fp32 LDS overlay (T0/T1 dead now)
#pragma unroll
  for (int ct = 0; ct < 8; ct++) {
    int j = (ct << 4) + nl;
#pragma unroll
    for (int r = 0; r < 4; r++) sm.O[lbase + r][j] = accO[ct][r] / zf[r];
  }
  __syncthreads();
  for (int idx = t; idx < 4096; idx += 512) { // full 512B-row coalesced stores
    int l = idx >> 5, g = (idx & 31) << 2;
    *(f32x4*)(outg + (((size_t)(n * Ln + l0c + l) * 8 + h) << 7) + g) = *(const f32x4*)&sm.O[l][g];
  }
}

extern "C" void kernel_launch(void* const* d_in, const int* in_sizes, int n_in,
                              void* d_out, int out_size, void* d_ws, size_t ws_size,
                              hipStream_t stream) {
  (void)in_sizes; (void)n_in; (void)out_size; (void)ws_size;
  const float* q   = (const float*)d_in[0];
  const float* q2  = (const float*)d_in[1];
  const float* kk  = (const float*)d_in[2];
  const float* vv  = (const float*)d_in[3];
  const float* kl  = (const float*)d_in[4];
  const float* om  = (const float*)d_in[5];
  float* out = (float*)d_out;

  // workspace carve (bf16 region then fp32 region) — ~171 MB
  u16* W     = (u16*)d_ws;
  u16* qb3   = W;                 // 3*NHLD
  u16* kb3   = W + 3 * NHLD;      // 3*NHLD (naturals; k_kvs keeps bits in regs for phase C)
  u16* vt    = W + 6 * NHLD;      // NHLD   (chunk-blocked [nh][c][i][sc])
  u16* sct   = W + 7 * NHLD;      // 3*NHLD (chunk sums -> exclusive prefix, in place)
  u16* wt    = W + 10 * NHLD;     // 131072 (omega^T bf16)
  float* ks  = (float*)(W + 10 * NHLD + 131072); // 196608 f32 (chunk Ksum -> prefix)
  float* osm = ks + 196608;       // 1024 f32
  float* zin = osm + 1024;        // 65536 f32 (Z_inter)

  k_omega <<<8,    256, 0, stream>>>(om, wt, osm);
  k_kvs   <<<512,  512, 0, stream>>>(kk, vv, kl, osm, kb3, vt, sct, ks);
  p1k     <<<48,   256, 0, stream>>>(ks);
  kqm     <<<1792, 256, 0, stream>>>(q2, q, wt, osm, ks, qb3, zin, sct);
  p3      <<<512,  512, 0, stream>>>(qb3, kb3, vt, sct, zin, out);
}

// Round 14
// 267.270 us; speedup vs baseline: 1.0243x; 1.0080x over previous
//
#include <hip/hip_runtime.h>

// CausalLinearRelativeAttention — chunked 3-branch causal linear attention, bf16 MFMA.
// N=4, L=2048, H=8, D=Dv=128, chunk C=128, T=16 chunks, 3 branches (coeff -2 folded into Qb2).
// R8: dropped kbt3. R11: k_kvfeat+p1a fused (k_kvs). R15: sct-prefix merged into kqm = 266.6us
//     (verified best). R16 (kvsp overlap) and R17 (register-staged KT) both regressed:
//     kvs window is BW-saturated, and the kb3 re-reads were L2-hot (free) — removing them
//     cost occupancy instead. R18: revert to exact R15.

typedef float f32x4 __attribute__((ext_vector_type(4)));
typedef short s16x8 __attribute__((ext_vector_type(8)));
typedef short s16x4 __attribute__((ext_vector_type(4)));
typedef unsigned short u16;

static constexpr int    Ln   = 2048;
static constexpr size_t NHLD = (size_t)32 * 2048 * 128; // per-branch feature elems = 8,388,608
static constexpr size_t KSB  = (size_t)32 * 16 * 128;   // kspre per-branch stride = 65536

__device__ __forceinline__ float b2f(u16 s) {
  union { unsigned u; float f; } x; x.u = ((unsigned)s) << 16; return x.f;
}
__device__ __forceinline__ u16 f2b(float f) {
  union { float f; unsigned u; } x; x.f = f;
  unsigned r = x.u + 0x7fffu + ((x.u >> 16) & 1u);
  return (u16)(r >> 16);
}
__device__ __forceinline__ s16x8 pack8(f32x4 a, f32x4 b) {
  s16x8 r;
  r[0] = (short)f2b(a[0]); r[1] = (short)f2b(a[1]); r[2] = (short)f2b(a[2]); r[3] = (short)f2b(a[3]);
  r[4] = (short)f2b(b[0]); r[5] = (short)f2b(b[1]); r[6] = (short)f2b(b[2]); r[7] = (short)f2b(b[3]);
  return r;
}

// ---------------------------------------------------------------- K0: omega^T (bf16) + column sums
__global__ __launch_bounds__(256) void k_omega(const float* __restrict__ om,
                                               u16* __restrict__ wt, float* __restrict__ osum) {
  __shared__ alignas(16) u16 T[128][136];
  int h = blockIdx.x, t = threadIdx.x;
  for (int idx = t; idx < 128 * 32; idx += 256) {
    int i = idx >> 5, cs = (idx & 31) << 2;
    f32x4 vv = *(const f32x4*)(om + ((size_t)(h * 128 + i)) * 128 + cs);
    T[i][cs + 0] = f2b(vv[0]); T[i][cs + 1] = f2b(vv[1]);
    T[i][cs + 2] = f2b(vv[2]); T[i][cs + 3] = f2b(vv[3]);
  }
  if (t < 128) { // exact fp32 column sums (coalesced per row)
    float acc = 0.f;
    for (int i = 0; i < 128; i++) acc += om[((size_t)(h * 128 + i)) * 128 + t];
    osum[h * 128 + t] = acc;
  }
  __syncthreads();
  { // transposed write: wt[h][j][i] = omega[h][i][j]
    int j = t >> 1, lh = (t & 1) << 6;
    s16x8* dst = (s16x8*)(wt + ((size_t)(h * 128 + j)) * 128 + lh);
    for (int u = 0; u < 8; u++) {
      s16x8 pv;
#pragma unroll
      for (int e = 0; e < 8; e++) pv[e] = (short)T[lh + u * 8 + e][j];
      dst[u] = pv;
    }
  }
}

// ---------------------- K1+P1a fused (k_kvs): one block per (n,h,c), 512 threads. (R11 verbatim)
__global__ __launch_bounds__(512) void k_kvs(const float* __restrict__ kg, const float* __restrict__ vg,
                                             const float* __restrict__ klg, const float* __restrict__ osum,
                                             u16* __restrict__ kb3, u16* __restrict__ vt,
                                             u16* __restrict__ sct, float* __restrict__ ksum) {
  __shared__ union {
    alignas(16) u16 VT[128][128]; // V natural [s][i], swizzled granules (phase A/B)
    alignas(16) u16 KT[128][136]; // Kb^T [i][s] swizzled; then S^T staging (phase C)
  } sm;
  int bid = blockIdx.x, t = threadIdx.x;
  int c = bid & 15, h = (bid >> 4) & 7, n = bid >> 7;
  int l0 = c << 7, nh = (n << 3) + h;
  const float invL = 1.0f / 2048.0f;
  int gcol = t & 31, cs = gcol << 2;          // column quad fixed per thread
  f32x4 osv = *(const f32x4*)(osum + h * 128 + cs);
  // ---- phase A: features + kb3 direct stores + VT build
#pragma unroll
  for (int it = 0; it < 8; it++) {
    int rr = (it << 4) + (t >> 5);            // row in chunk 0..127
    int l = l0 + rr;
    size_t gb = (((size_t)(n * Ln + l) * 8 + h) << 7) + cs;
    f32x4 kv = *(const f32x4*)(kg + gb);
    f32x4 vv = *(const f32x4*)(vg + gb);
    float klv = klg[n * Ln + l];
    float tb = (float)l * invL;
    u16 r0[4], r1[4], r2[4];
#pragma unroll
    for (int e = 0; e < 4; e++) {
      float kf = (kv[e] > 0.f ? kv[e] + 1.f : __expf(kv[e])) * klv;
      float tt = tb * osv[e];
      float s, cc; __sincosf(tt, &s, &cc);
      r0[e] = f2b(kf * cc * cc);
      r1[e] = f2b(kf * s * s);
      r2[e] = f2b(kf * s * cc);
    }
    int gs = (gcol ^ (rr >> 3)) << 2;         // swizzled granule (4 u16)
    *(s16x4*)&sm.VT[rr][gs] = (s16x4){(short)f2b(vv[0]), (short)f2b(vv[1]),
                                      (short)f2b(vv[2]), (short)f2b(vv[3])};
    size_t nb = ((size_t)nh * Ln + l) * 128 + cs;
    *(s16x4*)(kb3 + nb)          = (s16x4){(short)r0[0], (short)r0[1], (short)r0[2], (short)r0[3]};
    *(s16x4*)(kb3 + NHLD + nb)   = (s16x4){(short)r1[0], (short)r1[1], (short)r1[2], (short)r1[3]};
    *(s16x4*)(kb3 + 2*NHLD + nb) = (s16x4){(short)r2[0], (short)r2[1], (short)r2[2], (short)r2[3]};
  }
  __syncthreads();
  // ---- phase B: stream V^T chunk out (contiguous 32KB, full-line writes)
  size_t bv = ((size_t)(nh * 16 + c)) << 14;
  for (int idx = t; idx < 2048; idx += 512) {
    int i = idx >> 4, o = idx & 15;
    int gp = (((i >> 2) ^ o) << 2) + (i & 3);
    s16x8 v1;
#pragma unroll
    for (int u = 0; u < 8; u++) v1[u] = (short)sm.VT[(o << 3) + u][gp];
    *(s16x8*)(vt + bv + (((size_t)i) << 7) + (o << 3)) = v1;
  }
  // ---- phase C: per-branch chunk-S^T (operands L2-hot)
  int lane = t & 63, quad = lane >> 4, nl = lane & 15, w = t >> 6;
  int arow = (w << 4) + nl;                   // j row, 8 waves x 16 = 128
  const u16* vchunk = vt + bv;
  for (int b = 0; b < 3; b++) {
    int bnh = b * 32 + nh;
    const u16* kb = kb3 + (size_t)b * NHLD + ((size_t)nh * Ln + l0) * 128;
    __syncthreads();                          // VT reads / prev sct stream done before KT overwrite
    for (int idx = t; idx < 2048; idx += 512) {
      int s = idx >> 4, io = idx & 15;        // natural row s, i-octet io
      s16x8 v = *(const s16x8*)(kb + (((size_t)s) << 7) + (io << 3)); // L2-hot (own writes)
      int cp = s ^ ((io & 7) << 3);           // swizzled phys column
#pragma unroll
      for (int j = 0; j < 8; j++) sm.KT[(io << 3) + j][cp] = (u16)(short)v[j];
    }
    __syncthreads();
    f32x4 z4 = {0.f, 0.f, 0.f, 0.f};
    f32x4 acc[8];
#pragma unroll
    for (int i = 0; i < 8; i++) acc[i] = z4;
    for (int ks = 0; ks < 4; ks++) {
      int k0 = (ks << 5) + (quad << 3);
      s16x8 av = *(const s16x8*)(vchunk + (((size_t)arow) << 7) + k0); // L2-hot
#pragma unroll
      for (int ct = 0; ct < 8; ct++) {
        int r = (ct << 4) + nl;
        int koff = k0 ^ (((r >> 3) & 7) << 3); // unswizzle octet
        s16x8 bvv = *(const s16x8*)&sm.KT[r][koff];
        acc[ct] = __builtin_amdgcn_mfma_f32_16x16x32_bf16(av, bvv, acc[ct], 0, 0, 0);
      }
    }
    if (t < 128) { // ksum[i] = row-sum of Kb^T row i (swizzle-aware octet reads)
      float s = 0.f;
      int sw = ((t >> 3) & 7) << 3;
#pragma unroll 4
      for (int g = 0; g < 128; g += 8) {
        s16x8 v = *(const s16x8*)&sm.KT[t][g ^ sw];
#pragma unroll
        for (int e = 0; e < 8; e++) s += b2f((u16)v[e]);
      }
      ksum[(size_t)(bnh * 16 + c) * 128 + t] = s;
    }
    __syncthreads();
    { // C-layout -> KT (as S^T[j][i], plain layout)
      int lbase = (w << 4) + (quad << 2);
#pragma unroll
      for (int ct = 0; ct < 8; ct++) {
        int i = (ct << 4) + nl;
#pragma unroll
        for (int r = 0; r < 4; r++) sm.KT[lbase + r][i] = f2b(acc[ct][r]);
      }
    }
    __syncthreads();
    size_t sbase = ((size_t)(bnh * 16 + c)) << 14;
    for (int idx = t; idx < 2048; idx += 512) {
      int jr = idx >> 4, g = (idx & 15) << 3;
      *(s16x8*)(sct + sbase + ((size_t)jr << 7) + g) = *(const s16x8*)&sm.KT[jr][g];
    }
  }
}

// ---------------- P1k: ksum exclusive prefix over chunks (kqm's only prefix dependency)
__global__ __launch_bounds__(256) void p1k(float* __restrict__ ksum) {
  int m2 = blockIdx.x * 256 + threadIdx.x;  // 0..12287
  int i = m2 & 127, bnh = m2 >> 7;
  size_t base = (size_t)bnh * 2048 + i;
  float acc = 0.f;
  for (int c = 0; c < 16; c++) {
    size_t a = base + (size_t)c * 128;
    float v = ksum[a];
    ksum[a] = acc;
    acc += v;
  }
}

// ---------------- KQM: merged k_qfeat (blocks 0..1023) + sct exclusive prefix (blocks 1024..1791).
// The two workloads are independent; one dispatch overlaps the 96MB sct stream with k_qfeat.
__global__ __launch_bounds__(256, 2) void kqm(const float* __restrict__ q2g, const float* __restrict__ qg,
                                              const u16* __restrict__ wt, const float* __restrict__ osum,
                                              const float* __restrict__ kspre,
                                              u16* __restrict__ qb3, float* __restrict__ zintg,
                                              u16* __restrict__ sct) {
  __shared__ alignas(16) u16 B[128][136]; // omega^T[h]; later reused rows 0..63 for sin^2(proj)
  __shared__ float osb[128];
  int bid = blockIdx.x, t = threadIdx.x;
  if (bid >= 1024) { // ---- sct exclusive prefix over chunks (p1b body, verbatim)
    int tid = (bid - 1024) * 256 + t;  // 0..196607
    int bnh = tid >> 11, rem = tid & 2047;
    size_t base = ((size_t)bnh << 18) + ((size_t)rem << 3);
    float acc[8] = {0.f, 0.f, 0.f, 0.f, 0.f, 0.f, 0.f, 0.f};
    for (int c = 0; c < 16; c++) {
      size_t a = base + ((size_t)c << 14);
      s16x8 v = *(const s16x8*)(sct + a);
      s16x8 o;
#pragma unroll
      for (int e = 0; e < 8; e++) { o[e] = (short)f2b(acc[e]); acc[e] += b2f((u16)v[e]); }
      *(s16x8*)(sct + a) = o;
    }
    return;
  }
  // ---- k_qfeat body (R11 verbatim)
  int m = bid & 31, h = (bid >> 5) & 7, n = bid >> 8;
  int l0 = m << 6, c = m >> 1, nh = (n << 3) + h;
  if (t < 128) osb[t] = osum[h * 128 + t];
  for (int idx = t; idx < 2048; idx += 256) {
    int j = idx >> 4, cs = (idx & 15) << 3;
    *(s16x8*)&B[j][cs] = *(const s16x8*)(wt + ((size_t)(h * 128 + j)) * 128 + cs);
  }
  __syncthreads();
  int lane = t & 63, quad = lane >> 4, nl = lane & 15, w = t >> 6;
  f32x4 z4 = {0.f, 0.f, 0.f, 0.f};
  f32x4 acc[8];
#pragma unroll
  for (int i = 0; i < 8; i++) acc[i] = z4;
  int arow = l0 + (w << 4) + nl;
  for (int ks = 0; ks < 4; ks++) {
    int k0 = (ks << 5) + (quad << 3);
    const float* ap = q2g + (((size_t)(n * Ln + arow) * 8 + h) << 7) + k0;
    s16x8 av = pack8(*(const f32x4*)ap, *(const f32x4*)(ap + 4));
#pragma unroll
    for (int ct = 0; ct < 8; ct++) {
      s16x8 bv = *(const s16x8*)&B[(ct << 4) + nl][k0];
      acc[ct] = __builtin_amdgcn_mfma_f32_16x16x32_bf16(av, bv, acc[ct], 0, 0, 0);
    }
  }
  __syncthreads();
  { // sin^2(proj) -> B rows 0..63
    int lbase = (w << 4) + (quad << 2);
#pragma unroll
    for (int ct = 0; ct < 8; ct++) {
      int j = (ct << 4) + nl;
#pragma unroll
      for (int r = 0; r < 4; r++) {
        float sp = __sinf(acc[ct][r]);
        B[lbase + r][j] = f2b(sp * sp);
      }
    }
  }
  __syncthreads();
  const float invL = 1.0f / 2048.0f;
  for (int idx = t; idx < 1024; idx += 256) {
    int l = idx >> 4, j0 = (idx & 15) << 3, gl = l0 + l;
    s16x8 s2v = *(const s16x8*)&B[l][j0];
    const float* qp = qg + (((size_t)(n * Ln + gl) * 8 + h) << 7) + j0;
    f32x4 qa = *(const f32x4*)qp, qbv = *(const f32x4*)(qp + 4);
    size_t kbb = ((size_t)nh * 16 + c) * 128 + j0;
    f32x4 kp0a = *(const f32x4*)(kspre + kbb),           kp0b = *(const f32x4*)(kspre + kbb + 4);
    f32x4 kp1a = *(const f32x4*)(kspre + kbb + KSB),     kp1b = *(const f32x4*)(kspre + kbb + KSB + 4);
    f32x4 kp2a = *(const f32x4*)(kspre + kbb + 2 * KSB), kp2b = *(const f32x4*)(kspre + kbb + 2 * KSB + 4);
    s16x8 o0, o1, o2;
    float z = 0.f;
    float tb = (float)gl * invL;
#pragma unroll
    for (int e = 0; e < 8; e++) {
      float s2p = b2f((u16)s2v[e]);
      float qv = (e < 4) ? qa[e] : qbv[e - 4];
      float f = qv > 0.f ? qv + 1.f : __expf(qv);
      float Qt = s2p * f;
      float tt = tb * osb[j0 + e];
      float s, cc; __sincosf(tt, &s, &cc);
      float v0 = Qt * s * s, v1 = Qt * cc * cc, v2 = -2.f * Qt * s * cc;
      float k0v = (e < 4) ? kp0a[e] : kp0b[e - 4];
      float k1v = (e < 4) ? kp1a[e] : kp1b[e - 4];
      float k2v = (e < 4) ? kp2a[e] : kp2b[e - 4];
      z += v0 * k0v + v1 * k1v + v2 * k2v;
      o0[e] = (short)f2b(v0); o1[e] = (short)f2b(v1); o2[e] = (short)f2b(v2);
    }
    size_t base = ((size_t)nh * Ln + gl) * 128 + j0;
    *(s16x8*)(qb3 + base)            = o0;
    *(s16x8*)(qb3 + base + NHLD)     = o1;
    *(s16x8*)(qb3 + base + 2 * NHLD) = o2;
    z += __shfl_xor(z, 1); z += __shfl_xor(z, 2);
    z += __shfl_xor(z, 4); z += __shfl_xor(z, 8);
    if (nl == 0) zintg[(size_t)nh * Ln + gl] = z;
  }
}

// ---------------- P3: octet-XOR-swizzled stride-128 tiles, A-fragments hoisted pre-barrier.
// (R11 verbatim)
__global__ __launch_bounds__(512, 4) void p3(const u16* __restrict__ qb3, const u16* __restrict__ kb3,
                                             const u16* __restrict__ vtg, const u16* __restrict__ sct,
                                             const float* __restrict__ zintg, float* __restrict__ outg) {
  __shared__ union {
    struct { alignas(16) u16 T0[128][128]; alignas(16) u16 T1[128][128]; } s;
    alignas(16) float O[128][132];
  } sm;
  int bid = blockIdx.x, t = threadIdx.x;
  int c = bid & 15, h = (bid >> 4) & 7, n = bid >> 7;
  int l0c = c << 7, nh = (n << 3) + h;
  int lane = t & 63, quad = lane >> 4, nl = lane & 15, w = t >> 6;
  f32x4 z4 = {0.f, 0.f, 0.f, 0.f};
  f32x4 accP[8], accO[8];
#pragma unroll
  for (int i = 0; i < 8; i++) { accP[i] = z4; accO[i] = z4; }
  int arow = l0c + (w << 4) + nl;
  for (int b = 0; b < 3; b++) {
    int bnh = b * 32 + nh;
    __syncthreads();
    for (int idx = t; idx < 2048; idx += 512) { // T0 <- Kb chunk [s][i], swizzled octets
      int s = idx >> 4;
      int co = (((idx & 15) ^ (s & 7)) << 3);
      *(s16x8*)&sm.s.T0[s][co] = *(const s16x8*)(kb3 + (((size_t)bnh * Ln + l0c + s) << 7) + ((idx & 15) << 3));
    }
    size_t sbase = ((size_t)(bnh * 16 + c)) << 14;
    for (int idx = t; idx < 2048; idx += 512) { // T1 <- Sprefix^T [j][i], swizzled octets
      int j = idx >> 4;
      int co = (((idx & 15) ^ (j & 7)) << 3);
      *(s16x8*)&sm.s.T1[j][co] = *(const s16x8*)(sct + sbase + ((size_t)j << 7) + ((idx & 15) << 3));
    }
    s16x8 av[4]; // A-fragments issued before the barrier (latency hidden under staging)
#pragma unroll
    for (int ks = 0; ks < 4; ks++)
      av[ks] = *(const s16x8*)(qb3 + (((size_t)bnh * Ln + arow) << 7) + (ks << 5) + (quad << 3));
    __syncthreads();
    for (int ks = 0; ks < 4; ks++) {
      int k0 = (ks << 5) + (quad << 3);
#pragma unroll
      for (int ct = 0; ct < 8; ct++) {
        int r = (ct << 4) + nl;
        int koff = k0 ^ ((r & 7) << 3);       // unswizzle
        s16x8 bv0 = *(const s16x8*)&sm.s.T0[r][koff];
        accP[ct] = __builtin_amdgcn_mfma_f32_16x16x32_bf16(av[ks], bv0, accP[ct], 0, 0, 0);
        s16x8 bv1 = *(const s16x8*)&sm.s.T1[r][koff];
        accO[ct] = __builtin_amdgcn_mfma_f32_16x16x32_bf16(av[ks], bv1, accO[ct], 0, 0, 0);
      }
    }
  }
  __syncthreads();
  // masked P -> T0 as P[l][s] (bf16, swizzled) + register row-sums; stage T1 <- V^T [j][sc]
  float zP[4] = {0.f, 0.f, 0.f, 0.f};
  int lbase = (w << 4) + (quad << 2);
#pragma unroll
  for (int ct = 0; ct < 8; ct++) {
    int ss = (ct << 4) + nl;
#pragma unroll
    for (int r = 0; r < 4; r++) {
      int lr = lbase + r;
      float pv = (ss <= lr) ? accP[ct][r] : 0.f;
      zP[r] += pv;
      sm.s.T0[lr][ss ^ ((lr & 7) << 3)] = f2b(pv);
    }
  }
#pragma unroll
  for (int mteam = 1; mteam <= 8; mteam <<= 1) {
#pragma unroll
    for (int r = 0; r < 4; r++) zP[r] += __shfl_xor(zP[r], mteam);
  }
  size_t vbase = ((size_t)(nh * 16 + c)) << 14;
  for (int idx = t; idx < 2048; idx += 512) { // T1 <- V^T chunk (linear 32KB stream), swizzled
    int j = idx >> 4;
    int co = (((idx & 15) ^ (j & 7)) << 3);
    *(s16x8*)&sm.s.T1[j][co] = *(const s16x8*)(vtg + vbase + ((size_t)idx << 3));
  }
  float zf[4];
#pragma unroll
  for (int r = 0; r < 4; r++)
    zf[r] = zintg[(size_t)nh * Ln + l0c + lbase + r] + zP[r] + 1e-6f;
  __syncthreads();
  // intra: A = masked P (T0 rows l, k=s), B = V^T (T1 rows j, k=s)
  for (int ks = 0; ks < 4; ks++) {
    int k0 = (ks << 5) + (quad << 3);
    int rw = (w << 4) + nl;
    s16x8 pav = *(const s16x8*)&sm.s.T0[rw][k0 ^ ((rw & 7) << 3)];
#pragma unroll
    for (int ct = 0; ct < 8; ct++) {
      int r = (ct << 4) + nl;
      s16x8 vv = *(const s16x8*)&sm.s.T1[r][k0 ^ ((r & 7) << 3)];
      accO[ct] = __builtin_amdgcn_mfma_f32_16x16x32_bf16(pav, vv, accO[ct], 0, 0, 0);
    }
  }
  __syncthreads();
  // divided result -> fp32 LDS overlay (T0/T1 dead now)
#pragma unroll
  for (int ct = 0; ct < 8; ct++) {
    int j = (ct << 4) + nl;
#pragma unroll
    for (int r = 0; r < 4; r++) sm.O[lbase + r][j] = accO[ct][r] / zf[r];
  }
  __syncthreads();
  for (int idx = t; idx < 4096; idx += 512) { // full 512B-row coalesced stores
    int l = idx >> 5, g = (idx & 31) << 2;
    *(f32x4*)(outg + (((size_t)(n * Ln + l0c + l) * 8 + h) << 7) + g) = *(const f32x4*)&sm.O[l][g];
  }
}

extern "C" void kernel_launch(void* const* d_in, const int* in_sizes, int n_in,
                              void* d_out, int out_size, void* d_ws, size_t ws_size,
                              hipStream_t stream) {
  (void)in_sizes; (void)n_in; (void)out_size; (void)ws_size;
  const float* q   = (const float*)d_in[0];
  const float* q2  = (const float*)d_in[1];
  const float* kk  = (const float*)d_in[2];
  const float* vv  = (const float*)d_in[3];
  const float* kl  = (const float*)d_in[4];
  const float* om  = (const float*)d_in[5];
  float* out = (float*)d_out;

  // workspace carve (bf16 region then fp32 region) — ~171 MB
  u16* W     = (u16*)d_ws;
  u16* qb3   = W;                 // 3*NHLD
  u16* kb3   = W + 3 * NHLD;      // 3*NHLD (naturals; k_kvs transposes in-block, L2-hot)
  u16* vt    = W + 6 * NHLD;      // NHLD   (chunk-blocked [nh][c][i][sc])
  u16* sct   = W + 7 * NHLD;      // 3*NHLD (chunk sums -> exclusive prefix, in place)
  u16* wt    = W + 10 * NHLD;     // 131072 (omega^T bf16)
  float* ks  = (float*)(W + 10 * NHLD + 131072); // 196608 f32 (chunk Ksum -> prefix)
  float* osm = ks + 196608;       // 1024 f32
  float* zin = osm + 1024;        // 65536 f32 (Z_inter)

  k_omega <<<8,    256, 0, stream>>>(om, wt, osm);
  k_kvs   <<<512,  512, 0, stream>>>(kk, vv, kl, osm, kb3, vt, sct, ks);
  p1k     <<<48,   256, 0, stream>>>(ks);
  kqm     <<<1792, 256, 0, stream>>>(q2, q, wt, osm, ks, qb3, zin, sct);
  p3      <<<512,  512, 0, stream>>>(qb3, kb3, vt, sct, zin, out);
}